// Round 15
// baseline (82.532 us; speedup 1.0000x reference)
//
#include <hip/hip_runtime.h>

#define DEV __device__ __forceinline__

typedef __bf16 bf16x8 __attribute__((ext_vector_type(8)));
typedef unsigned short u16x8v __attribute__((ext_vector_type(8)));
typedef float f32x4 __attribute__((ext_vector_type(4)));
typedef float f32x16 __attribute__((ext_vector_type(16)));
typedef unsigned int u32x4v __attribute__((ext_vector_type(4)));
typedef unsigned short u16;
typedef unsigned int u32;

// f32 -> bf16 bits, round-to-nearest-even (validated R1-R14, all signs)
DEV u16 f2bf(float f) {
    u32 u = __builtin_bit_cast(u32, f);
    u = (u + 0x7FFFu + ((u >> 16) & 1u)) >> 16;
    return (u16)u;
}

DEV float bf2f(u16 v) {
    return __builtin_bit_cast(float, (u32)v << 16);
}

DEV bf16x8 ld_bf8(const u16* p) {
    return *reinterpret_cast<const bf16x8*>(p);
}

// 8B-alignment-safe 16B LDS read (rows padded to 8B multiples, not 16B)
DEV bf16x8 ld_lds8(const u16* p) {
    ushort4 a = *reinterpret_cast<const ushort4*>(p);
    ushort4 b = *reinterpret_cast<const ushort4*>(p + 4);
    u16x8v o;
    o[0] = a.x; o[1] = a.y; o[2] = a.z; o[3] = a.w;
    o[4] = b.x; o[5] = b.y; o[6] = b.z; o[7] = b.w;
    return __builtin_bit_cast(bf16x8, o);
}

// raw v_exp_f32 (validated R10)
DEV float fexp2(float x) { return __builtin_amdgcn_exp2f(x); }

// pack two f32 -> one u32 of 2 bf16 (lo=a, hi=b).  Validated ONLY for a,b>=0.
DEV u32 cvt_pk_bf16(float a, float b) {
    u32 r;
    asm("v_cvt_pk_bf16_f32 %0, %1, %2" : "=v"(r) : "v"(a), "v"(b));
    return r;
}

// NOTE: v_permlane32_swap_b32 is BANNED (R5, R12 both failed absmax 0.71).

// ---------------------------------------------------------------------------
// Kernel 1: prep.  Blocks [0,384): weight transpose+convert (Wq pre-scaled by
// 1/sqrt(512)*log2(e)).  Blocks [384,386): build 144-entry chunk table:
// q-block j (tiles 4j..4j+3) has (j>>2)+1 chunks of 16 subtiles.
// ---------------------------------------------------------------------------
__global__ __launch_bounds__(256) void prep_kernel(const float* __restrict__ W0,
                                                   const float* __restrict__ W1,
                                                   const float* __restrict__ W2,
                                                   u16* __restrict__ Wt,
                                                   u32* __restrict__ table) {
    const int blk = blockIdx.x;
    if (blk < 384) {
        int idx = blk * 256 + threadIdx.x;   // 3*64*512 = 98304
        int w = idx >> 15, rem = idx & 32767, h = rem >> 9, c = rem & 511;
        const float* W = (w == 0) ? W0 : ((w == 1) ? W1 : W2);
        float v = W[c * 64 + h];
        if (w == 0) v *= 0.044194173824159216f * 1.4426950408889634f;  // SCL*log2e
        Wt[idx] = f2bf(v);
    } else {
        int idx = (blk - 384) * 256 + threadIdx.x;   // < 512
        if (idx < 512) {
            int j = idx >> 4, k = idx & 15;          // j = 0..31
            int nch = (j >> 2) + 1;
            if (k < nch) {
                int base = 0;
                for (int i = 0; i < j; ++i) base += (i >> 2) + 1;
                table[base + k] = (u32)j | ((u32)k << 16);
            }
        }
    }
}

// ---------------------------------------------------------------------------
// Kernel 2: QKV projection, whole-slab LDS staging: stage 64x512 x (f32->bf16)
// ONCE (32 streamed float4 loads/thread), one barrier, then 16 kk x 12 MFMA.
// 256 blocks x 256 threads; math identical to R11-validated version.
// ---------------------------------------------------------------------------
__global__ __launch_bounds__(256) void proj_kernel(const float* __restrict__ x,
                                                   const u16* __restrict__ Wt,
                                                   u16* __restrict__ Q,
                                                   u16* __restrict__ Kq,
                                                   u16* __restrict__ Vt) {
    __shared__ __align__(16) u16 xs[64 * 524];   // pitch 524 u16: 2-way banks
    const int tid = threadIdx.x;
    const int wave = tid >> 6, lane = tid & 63;
    const int lr = lane & 15, lg = lane >> 4;
    const int r0 = blockIdx.x * 64;

    // stage: 8192 float4 units; unit u: row = u>>7, col4 = u&127
#pragma unroll
    for (int p = 0; p < 32; ++p) {
        const int u = tid + p * 256;
        const int row = u >> 7, col4 = u & 127;
        float4 a = *reinterpret_cast<const float4*>(x + (size_t)(r0 + row) * 512 + col4 * 4);
        ushort4 hv;
        hv.x = f2bf(a.x); hv.y = f2bf(a.y); hv.z = f2bf(a.z); hv.w = f2bf(a.w);
        *reinterpret_cast<ushort4*>(&xs[row * 524 + col4 * 4]) = hv;
    }
    __syncthreads();

    f32x4 acc[3][4];
#pragma unroll
    for (int m = 0; m < 3; ++m)
#pragma unroll
        for (int b = 0; b < 4; ++b) acc[m][b] = (f32x4){0.f, 0.f, 0.f, 0.f};

    for (int kk = 0; kk < 16; ++kk) {
        bf16x8 af = ld_lds8(&xs[(wave * 16 + lr) * 524 + kk * 32 + lg * 8]);
#pragma unroll
        for (int m = 0; m < 3; ++m) {
#pragma unroll
            for (int nt = 0; nt < 4; ++nt) {
                bf16x8 bf = ld_bf8(Wt + m * 32768 + (lr + 16 * nt) * 512 + kk * 32 + lg * 8);
                acc[m][nt] = __builtin_amdgcn_mfma_f32_16x16x32_bf16(af, bf, acc[m][nt], 0, 0, 0);
            }
        }
    }

    const int rw = r0 + wave * 16;
#pragma unroll
    for (int nt = 0; nt < 4; ++nt) {
        const int h = lr + 16 * nt;
#pragma unroll
        for (int reg = 0; reg < 4; ++reg) {
            Q[(size_t)(rw + 4 * lg + reg) * 64 + h]  = f2bf(acc[0][nt][reg]);
            Kq[(size_t)(rw + 4 * lg + reg) * 64 + h] = f2bf(acc[1][nt][reg]);
        }
    }
    const int bidx = rw >> 12;
    const int t0 = (rw & 4095) + 4 * lg;
#pragma unroll
    for (int nt = 0; nt < 4; ++nt) {
        const int h = lr + 16 * nt;
        ushort4 hv;
        hv.x = f2bf(acc[2][nt][0]); hv.y = f2bf(acc[2][nt][1]);
        hv.z = f2bf(acc[2][nt][2]); hv.w = f2bf(acc[2][nt][3]);
        *reinterpret_cast<ushort4*>(Vt + ((size_t)(bidx * 64 + h)) * 4096 + t0) = hv;
    }
}

// ---------------------------------------------------------------------------
// Attention math helpers (byte-identical to R13/R14-validated versions)
// ---------------------------------------------------------------------------
DEV void mask_diag(f32x16& st, int q31, int hi) {
#pragma unroll
    for (int reg = 0; reg < 16; ++reg) {
        const int crow = (reg & 3) + 8 * (reg >> 2) + 4 * hi;
        if (crow > q31) st[reg] = -3.0e38f;
    }
}

DEV float max16(const f32x16& a) {
    float m0 = fmaxf(fmaxf(a[0], a[1]), a[2]);
    float m1 = fmaxf(fmaxf(a[3], a[4]), a[5]);
    float m2 = fmaxf(fmaxf(a[6], a[7]), a[8]);
    float m3 = fmaxf(fmaxf(a[9], a[10]), a[11]);
    float m4 = fmaxf(fmaxf(a[12], a[13]), a[14]);
    float m5 = fmaxf(fmaxf(m0, m1), a[15]);
    float m6 = fmaxf(fmaxf(m2, m3), m4);
    return fmaxf(m5, m6);
}

DEV float expsum(f32x16& st, float m) {
    float r0 = 0.f, r1 = 0.f, r2 = 0.f, r3 = 0.f;
#pragma unroll
    for (int g = 0; g < 4; ++g) {
        float p0 = fexp2(st[4 * g + 0] - m);
        float p1 = fexp2(st[4 * g + 1] - m);
        float p2 = fexp2(st[4 * g + 2] - m);
        float p3 = fexp2(st[4 * g + 3] - m);
        st[4 * g + 0] = p0; st[4 * g + 1] = p1;
        st[4 * g + 2] = p2; st[4 * g + 3] = p3;
        r0 += p0; r1 += p1; r2 += p2; r3 += p3;
    }
    return (r0 + r1) + (r2 + r3);
}

DEV void packP(const f32x16& st, bf16x8& pb0, bf16x8& pb1, int hi) {
    u32 A0 = cvt_pk_bf16(st[0], st[1]),  A1 = cvt_pk_bf16(st[2], st[3]);
    u32 A2 = cvt_pk_bf16(st[4], st[5]),  A3 = cvt_pk_bf16(st[6], st[7]);
    u32 A4 = cvt_pk_bf16(st[8], st[9]),  A5 = cvt_pk_bf16(st[10], st[11]);
    u32 A6 = cvt_pk_bf16(st[12], st[13]), A7 = cvt_pk_bf16(st[14], st[15]);
    u32 e0 = __shfl_xor(hi ? A0 : A2, 32, 64);
    u32 e1 = __shfl_xor(hi ? A1 : A3, 32, 64);
    u32 e2 = __shfl_xor(hi ? A4 : A6, 32, 64);
    u32 e3 = __shfl_xor(hi ? A5 : A7, 32, 64);
    u32x4v w0, w1;
    w0[0] = hi ? e0 : A0;
    w0[1] = hi ? e1 : A1;
    w0[2] = hi ? A2 : e0;
    w0[3] = hi ? A3 : e1;
    w1[0] = hi ? e2 : A4;
    w1[1] = hi ? e3 : A5;
    w1[2] = hi ? A6 : e2;
    w1[3] = hi ? A7 : e3;
    pb0 = __builtin_bit_cast(bf16x8, w0);
    pb1 = __builtin_bit_cast(bf16x8, w1);
}

// ---------------------------------------------------------------------------
// Kernel 3: causal flash attention, 4-wave q-block, double-buffered LDS-staged
// 64-KEY PAIRS (2 subtiles per buffer): half the iterations/barriers of R14.
// Block = tiles 4j..4j+3 (batch b = bid&3); chunk = 16 subtiles (CS=16).
// Wave computes stA (keys 0..31 of pair) if s<=qi, stB (32..63) if s+1<=qi,
// sharing one rescale check (R8-validated 2-ILP pattern).
// Partials bf16, 16-slot layout (c <= 7); merge nc = (qi>>4)+1.
// ---------------------------------------------------------------------------
__global__ __launch_bounds__(256) void attn_part_kernel(const u16* __restrict__ Q,
                                                        const u16* __restrict__ K,
                                                        const u16* __restrict__ Vt,
                                                        const u32* __restrict__ table,
                                                        u16* __restrict__ Opart,
                                                        float* __restrict__ Mpart,
                                                        float* __restrict__ Lpart) {
    __shared__ __align__(16) u16 Ks[2][64][68];   // [buf][key 0..63][d 0..63 +4]
    __shared__ __align__(16) u16 Vs[2][64][68];   // [buf][d 0..63][t 0..63 +4]

    const int tid = threadIdx.x;
    const int wave = tid >> 6, lane = tid & 63;
    const int q31 = lane & 31, hi = lane >> 5;
    const int bid = blockIdx.x;
    const int b = bid & 3;
    const u32 e = table[bid >> 2];
    const int j = (int)(e & 0xffff);
    const int c = (int)(e >> 16);
    const int qi = 4 * j + wave;
    const int qr0 = qi * 32;
    const int s0 = c * 16;
    const int s1 = min(4 * j + 4, s0 + 16);   // even - even => pair-aligned
    const int tile = (b << 7) | qi;

    const u16* Qb = Q + (size_t)b * 4096 * 64;
    const u16* Kb = K + (size_t)b * 4096 * 64;
    const u16* Vb = Vt + (size_t)b * 64 * 4096;

    // staging coords: unit u = tid (+256): row = u>>3 (0..63), c8 = (u&7)*8
    const int ur = tid >> 3, uc = (tid & 7) * 8;
    const u16* ksrc = Kb + (size_t)ur * 64 + uc;          // + s*2048 (+2048 for pass 1)
    const u16* vsrc = Vb + (size_t)ur * 4096 + uc;        // + s*32
    u16* kdst0 = &Ks[0][ur][uc];
    u16* vdst0 = &Vs[0][ur][uc];
    const u16* vsrc1 = Vb + (size_t)(32 + ur) * 4096 + uc;
    u16* kdst1 = &Ks[0][32 + ur][uc];
    u16* vdst1 = &Vs[0][32 + ur][uc];
    const size_t bufstep = (size_t)(&Ks[1][0][0] - &Ks[0][0][0]);  // == 64*68

#define LOADPAIR(S)                                                             \
    {   const int kv = (S) * 2048, tv = (S) * 32;                               \
        pk0 = *reinterpret_cast<const uint4*>(ksrc + kv);                       \
        pk1 = *reinterpret_cast<const uint4*>(ksrc + kv + 2048);                \
        pv0 = *reinterpret_cast<const uint4*>(vsrc + tv);                       \
        pv1 = *reinterpret_cast<const uint4*>(vsrc1 + tv);  }

#define WRITEBUF(BUF)                                                           \
    {   const size_t o = (BUF) * bufstep;                                       \
        *reinterpret_cast<uint4*>(kdst0 + o) = pk0;                             \
        *reinterpret_cast<uint4*>(kdst1 + o) = pk1;                             \
        *reinterpret_cast<uint4*>(vdst0 + o) = pv0;                             \
        *reinterpret_cast<uint4*>(vdst1 + o) = pv1;  }

    bf16x8 qf[4];
#pragma unroll
    for (int kk = 0; kk < 4; ++kk)
        qf[kk] = ld_bf8(Qb + (size_t)(qr0 + q31) * 64 + kk * 16 + hi * 8);

    f32x16 o0, o1;
#pragma unroll
    for (int r = 0; r < 16; ++r) { o0[r] = 0.f; o1[r] = 0.f; }
    float m_run = -1.0e30f, l_run = 0.f;

    uint4 pk0, pk1, pv0, pv1;
    LOADPAIR(s0);
    WRITEBUF(0);
    if (s0 + 2 < s1) LOADPAIR(s0 + 2);
    __syncthreads();

    for (int s = s0; s < s1; s += 2) {
        const int pb = ((s - s0) >> 1) & 1;
        if (s + 2 < s1) {
            WRITEBUF(pb ^ 1);
            if (s + 4 < s1) LOADPAIR(s + 4);
        }

        if (s <= qi) {                         // wave-uniform
            const bool doB = (s + 1 <= qi);
            f32x16 stA;
#pragma unroll
            for (int r = 0; r < 16; ++r) stA[r] = 0.f;
#pragma unroll
            for (int kk = 0; kk < 4; ++kk) {
                bf16x8 kf = ld_lds8(&Ks[pb][q31][kk * 16 + hi * 8]);
                stA = __builtin_amdgcn_mfma_f32_32x32x16_bf16(kf, qf[kk], stA, 0, 0, 0);
            }
            if (s == qi) mask_diag(stA, q31, hi);
            f32x16 stB;
            if (doB) {
#pragma unroll
                for (int r = 0; r < 16; ++r) stB[r] = 0.f;
#pragma unroll
                for (int kk = 0; kk < 4; ++kk) {
                    bf16x8 kf = ld_lds8(&Ks[pb][32 + q31][kk * 16 + hi * 8]);
                    stB = __builtin_amdgcn_mfma_f32_32x32x16_bf16(kf, qf[kk], stB, 0, 0, 0);
                }
                if (s + 1 == qi) mask_diag(stB, q31, hi);
            }

            float pm = max16(stA);
            if (doB) pm = fmaxf(pm, max16(stB));
            pm = fmaxf(pm, __shfl_xor(pm, 32, 64));
            if (!__all(pm - m_run <= 11.5f)) {
                float mn = fmaxf(m_run, pm);
                float al = fexp2(m_run - mn);
                m_run = mn;
                l_run *= al;
#pragma unroll
                for (int r = 0; r < 16; ++r) { o0[r] *= al; o1[r] *= al; }
            }
            float rs = expsum(stA, m_run);
            if (doB) rs += expsum(stB, m_run);
            rs += __shfl_xor(rs, 32, 64);
            l_run += rs;

            bf16x8 p0, p1;
            packP(stA, p0, p1, hi);
            {
                bf16x8 va = ld_lds8(&Vs[pb][q31][hi * 8]);
                bf16x8 vb2 = ld_lds8(&Vs[pb][q31][16 + hi * 8]);
                bf16x8 vc = ld_lds8(&Vs[pb][32 + q31][hi * 8]);
                bf16x8 vd = ld_lds8(&Vs[pb][32 + q31][16 + hi * 8]);
                o0 = __builtin_amdgcn_mfma_f32_32x32x16_bf16(va, p0, o0, 0, 0, 0);
                o0 = __builtin_amdgcn_mfma_f32_32x32x16_bf16(vb2, p1, o0, 0, 0, 0);
                o1 = __builtin_amdgcn_mfma_f32_32x32x16_bf16(vc, p0, o1, 0, 0, 0);
                o1 = __builtin_amdgcn_mfma_f32_32x32x16_bf16(vd, p1, o1, 0, 0, 0);
            }
            if (doB) {
                packP(stB, p0, p1, hi);
                bf16x8 va = ld_lds8(&Vs[pb][q31][32 + hi * 8]);
                bf16x8 vb2 = ld_lds8(&Vs[pb][q31][48 + hi * 8]);
                bf16x8 vc = ld_lds8(&Vs[pb][32 + q31][32 + hi * 8]);
                bf16x8 vd = ld_lds8(&Vs[pb][32 + q31][48 + hi * 8]);
                o0 = __builtin_amdgcn_mfma_f32_32x32x16_bf16(va, p0, o0, 0, 0, 0);
                o0 = __builtin_amdgcn_mfma_f32_32x32x16_bf16(vb2, p1, o0, 0, 0, 0);
                o1 = __builtin_amdgcn_mfma_f32_32x32x16_bf16(vc, p0, o1, 0, 0, 0);
                o1 = __builtin_amdgcn_mfma_f32_32x32x16_bf16(vd, p1, o1, 0, 0, 0);
            }
        }
        __syncthreads();
    }
#undef LOADPAIR
#undef WRITEBUF

    if (s0 <= qi) {
        const size_t base = (size_t)(tile * 16 + c);
        u16* Op = Opart + base * 2048;
#pragma unroll
        for (int reg = 0; reg < 16; ++reg) {
            const int crow = (reg & 3) + 8 * (reg >> 2) + 4 * hi;
            Op[crow * 32 + q31] = f2bf(o0[reg]);
            Op[(32 + crow) * 32 + q31] = f2bf(o1[reg]);
        }
        if (lane < 32) {
            Mpart[base * 32 + lane] = m_run;
            Lpart[base * 32 + lane] = l_run;
        }
    }
}

// ---------------------------------------------------------------------------
// Kernel 4: merge partials (bf16 Opart).  One block per q-tile (512 blocks).
// Double-buffered LDS + next-chunk prefetch.  nc = (qi>>4)+1 (CS=16).
// ---------------------------------------------------------------------------
__global__ __launch_bounds__(256) void merge_kernel(const u16* __restrict__ Opart,
                                                    const float* __restrict__ Mpart,
                                                    const float* __restrict__ Lpart,
                                                    float* __restrict__ out) {
    __shared__ float ld[2][64 * 33];
    const int tile = blockIdx.x;            // 0..511
    const int tid = threadIdx.x;
    const int q = tid >> 3, dg = tid & 7;
    const int qi = tile & 127;
    const int nc = (qi >> 4) + 1;           // chunks of 16 subtiles

    float M = -3.0e38f;
    for (int c = 0; c < nc; ++c)
        M = fmaxf(M, Mpart[(tile * 16 + c) * 32 + q]);

    float L = 0.f;
    float acc[8];
#pragma unroll
    for (int j = 0; j < 8; ++j) acc[j] = 0.f;

    const int drow = tid >> 2;
    const int qq = (tid & 3) * 8;

    u16x8v v = reinterpret_cast<const u16x8v*>(Opart + (size_t)(tile * 16) * 2048)[tid];

    for (int c = 0; c < nc; ++c) {
        const size_t base = (size_t)(tile * 16 + c);
        {
            float* dst = &ld[c & 1][drow * 33 + qq];
#pragma unroll
            for (int j = 0; j < 8; ++j) dst[j] = bf2f(v[j]);
        }
        const int cn = (c + 1 < nc) ? c + 1 : c;
        v = reinterpret_cast<const u16x8v*>(Opart + (size_t)(tile * 16 + cn) * 2048)[tid];

        __syncthreads();
        float w = fexp2(Mpart[base * 32 + q] - M);
        L += w * Lpart[base * 32 + q];
        const float* src = &ld[c & 1][0];
#pragma unroll
        for (int j = 0; j < 8; ++j)
            acc[j] += w * src[(dg * 8 + j) * 33 + q];
    }

    const float inv = 1.0f / L;
    float4 r0, r1;
    r0.x = acc[0] * inv; r0.y = acc[1] * inv; r0.z = acc[2] * inv; r0.w = acc[3] * inv;
    r1.x = acc[4] * inv; r1.y = acc[5] * inv; r1.z = acc[6] * inv; r1.w = acc[7] * inv;
    float4* dst = reinterpret_cast<float4*>(out + ((size_t)(tile * 32 + q)) * 64 + dg * 8);
    dst[0] = r0;
    dst[1] = r1;
}

// ---------------------------------------------------------------------------
extern "C" void kernel_launch(void* const* d_in, const int* in_sizes, int n_in,
                              void* d_out, int out_size, void* d_ws, size_t ws_size,
                              hipStream_t stream) {
    const float* x  = (const float*)d_in[0];
    const float* Wq = (const float*)d_in[1];
    const float* Wk = (const float*)d_in[2];
    const float* Wv = (const float*)d_in[3];
    float* out = (float*)d_out;

    char* ws = (char*)d_ws;
    const size_t MB = 1024 * 1024;
    u16* Qw  = (u16*)(ws);                     // 2 MiB
    u16* Kw  = (u16*)(ws + 2 * MB);            // 2 MiB
    u16* Vtw = (u16*)(ws + 4 * MB);            // 2 MiB
    u16* Wt  = (u16*)(ws + 6 * MB);            // 192 KiB
    u32* table = (u32*)(ws + 7 * MB);          // 576 B (144 entries)

    u16* Opart = (u16*)(ws + 8 * MB);          // 16 slots x 512 x 4KB = 32 MiB
    float* Mpart = (float*)(ws + 8 * MB + 32 * MB);
    float* Lpart = Mpart + (size_t)16 * 512 * 32;

    prep_kernel<<<386, 256, 0, stream>>>(Wq, Wk, Wv, Wt, table);
    proj_kernel<<<256, 256, 0, stream>>>(x, Wt, Qw, Kw, Vtw);
    attn_part_kernel<<<4 * 144, 256, 0, stream>>>(Qw, Kw, Vtw, table, Opart, Mpart, Lpart);
    merge_kernel<<<512, 256, 0, stream>>>(Opart, Mpart, Lpart, out);
}

// Round 16
// 72.895 us; speedup vs baseline: 1.1322x; 1.1322x over previous
//
#include <hip/hip_runtime.h>

#define DEV __device__ __forceinline__

typedef __bf16 bf16x8 __attribute__((ext_vector_type(8)));
typedef unsigned short u16x8v __attribute__((ext_vector_type(8)));
typedef float f32x4 __attribute__((ext_vector_type(4)));
typedef float f32x16 __attribute__((ext_vector_type(16)));
typedef unsigned int u32x4v __attribute__((ext_vector_type(4)));
typedef unsigned short u16;
typedef unsigned int u32;

// f32 -> bf16 bits, round-to-nearest-even (validated R1-R15, all signs)
DEV u16 f2bf(float f) {
    u32 u = __builtin_bit_cast(u32, f);
    u = (u + 0x7FFFu + ((u >> 16) & 1u)) >> 16;
    return (u16)u;
}

DEV float bf2f(u16 v) {
    return __builtin_bit_cast(float, (u32)v << 16);
}

DEV bf16x8 ld_bf8(const u16* p) {
    return *reinterpret_cast<const bf16x8*>(p);
}

// 8B-alignment-safe 16B LDS read (rows padded to 8B multiples, not 16B)
DEV bf16x8 ld_lds8(const u16* p) {
    ushort4 a = *reinterpret_cast<const ushort4*>(p);
    ushort4 b = *reinterpret_cast<const ushort4*>(p + 4);
    u16x8v o;
    o[0] = a.x; o[1] = a.y; o[2] = a.z; o[3] = a.w;
    o[4] = b.x; o[5] = b.y; o[6] = b.z; o[7] = b.w;
    return __builtin_bit_cast(bf16x8, o);
}

// raw v_exp_f32 (validated R10)
DEV float fexp2(float x) { return __builtin_amdgcn_exp2f(x); }

// pack two f32 -> one u32 of 2 bf16 (lo=a, hi=b).  Validated ONLY for a,b>=0.
DEV u32 cvt_pk_bf16(float a, float b) {
    u32 r;
    asm("v_cvt_pk_bf16_f32 %0, %1, %2" : "=v"(r) : "v"(a), "v"(b));
    return r;
}

// NOTE: v_permlane32_swap_b32 is BANNED (R5, R12 both failed absmax 0.71).
// NOTE: occupancy gate (R15 lesson): attn LDS 17.9KB (8 blk/CU), proj 5KB.

// ---------------------------------------------------------------------------
// Kernel 1: prep.  Blocks [0,384): weight transpose+convert (Wq pre-scaled by
// 1/sqrt(512)*log2(e)).  Blocks [384,386): build 144-entry chunk table:
// q-block j (tiles 4j..4j+3) has (j>>2)+1 chunks of 16 subtiles (CS=16,
// validated R15).
// ---------------------------------------------------------------------------
__global__ __launch_bounds__(256) void prep_kernel(const float* __restrict__ W0,
                                                   const float* __restrict__ W1,
                                                   const float* __restrict__ W2,
                                                   u16* __restrict__ Wt,
                                                   u32* __restrict__ table) {
    const int blk = blockIdx.x;
    if (blk < 384) {
        int idx = blk * 256 + threadIdx.x;   // 3*64*512 = 98304
        int w = idx >> 15, rem = idx & 32767, h = rem >> 9, c = rem & 511;
        const float* W = (w == 0) ? W0 : ((w == 1) ? W1 : W2);
        float v = W[c * 64 + h];
        if (w == 0) v *= 0.044194173824159216f * 1.4426950408889634f;  // SCL*log2e
        Wt[idx] = f2bf(v);
    } else {
        int idx = (blk - 384) * 256 + threadIdx.x;   // < 512
        if (idx < 512) {
            int j = idx >> 4, k = idx & 15;          // j = 0..31
            int nch = (j >> 2) + 1;
            if (k < nch) {
                int base = 0;
                for (int i = 0; i < j; ++i) base += (i >> 2) + 1;
                table[base + k] = (u32)j | ((u32)k << 16);
            }
        }
    }
}

// ---------------------------------------------------------------------------
// Kernel 2: QKV projection, per-kk LDS-staged x (validated R11/R14; 5KB LDS).
// ---------------------------------------------------------------------------
__global__ __launch_bounds__(256) void proj_kernel(const float* __restrict__ x,
                                                   const u16* __restrict__ Wt,
                                                   u16* __restrict__ Q,
                                                   u16* __restrict__ Kq,
                                                   u16* __restrict__ Vt) {
    __shared__ __align__(16) u16 xs[64 * 40];
    const int tid = threadIdx.x;
    const int wave = tid >> 6, lane = tid & 63;
    const int lr = lane & 15, lg = lane >> 4;
    const int r0 = blockIdx.x * 64;
    const int srow = tid >> 3, scol = (tid & 7) * 4;

    f32x4 acc[3][4];
#pragma unroll
    for (int m = 0; m < 3; ++m)
#pragma unroll
        for (int b = 0; b < 4; ++b) acc[m][b] = (f32x4){0.f, 0.f, 0.f, 0.f};

    for (int kk = 0; kk < 16; ++kk) {
#pragma unroll
        for (int p = 0; p < 2; ++p) {
            const int row = p * 32 + srow;
            float4 a = *reinterpret_cast<const float4*>(
                x + (size_t)(r0 + row) * 512 + kk * 32 + scol);
            ushort4 hv;
            hv.x = f2bf(a.x); hv.y = f2bf(a.y); hv.z = f2bf(a.z); hv.w = f2bf(a.w);
            *reinterpret_cast<ushort4*>(&xs[row * 40 + scol]) = hv;
        }
        __syncthreads();

        bf16x8 af = ld_bf8(&xs[(wave * 16 + lr) * 40 + lg * 8]);
#pragma unroll
        for (int m = 0; m < 3; ++m) {
#pragma unroll
            for (int nt = 0; nt < 4; ++nt) {
                bf16x8 bf = ld_bf8(Wt + m * 32768 + (lr + 16 * nt) * 512 + kk * 32 + lg * 8);
                acc[m][nt] = __builtin_amdgcn_mfma_f32_16x16x32_bf16(af, bf, acc[m][nt], 0, 0, 0);
            }
        }
        __syncthreads();
    }

    const int rw = r0 + wave * 16;
#pragma unroll
    for (int nt = 0; nt < 4; ++nt) {
        const int h = lr + 16 * nt;
#pragma unroll
        for (int reg = 0; reg < 4; ++reg) {
            Q[(size_t)(rw + 4 * lg + reg) * 64 + h]  = f2bf(acc[0][nt][reg]);
            Kq[(size_t)(rw + 4 * lg + reg) * 64 + h] = f2bf(acc[1][nt][reg]);
        }
    }
    const int bidx = rw >> 12;
    const int t0 = (rw & 4095) + 4 * lg;
#pragma unroll
    for (int nt = 0; nt < 4; ++nt) {
        const int h = lr + 16 * nt;
        ushort4 hv;
        hv.x = f2bf(acc[2][nt][0]); hv.y = f2bf(acc[2][nt][1]);
        hv.z = f2bf(acc[2][nt][2]); hv.w = f2bf(acc[2][nt][3]);
        *reinterpret_cast<ushort4*>(Vt + ((size_t)(bidx * 64 + h)) * 4096 + t0) = hv;
    }
}

// ---------------------------------------------------------------------------
// Attention math helpers (byte-identical to R13/R14-validated versions)
// ---------------------------------------------------------------------------
DEV void mask_diag(f32x16& st, int q31, int hi) {
#pragma unroll
    for (int reg = 0; reg < 16; ++reg) {
        const int crow = (reg & 3) + 8 * (reg >> 2) + 4 * hi;
        if (crow > q31) st[reg] = -3.0e38f;
    }
}

DEV float max16(const f32x16& a) {
    float m0 = fmaxf(fmaxf(a[0], a[1]), a[2]);
    float m1 = fmaxf(fmaxf(a[3], a[4]), a[5]);
    float m2 = fmaxf(fmaxf(a[6], a[7]), a[8]);
    float m3 = fmaxf(fmaxf(a[9], a[10]), a[11]);
    float m4 = fmaxf(fmaxf(a[12], a[13]), a[14]);
    float m5 = fmaxf(fmaxf(m0, m1), a[15]);
    float m6 = fmaxf(fmaxf(m2, m3), m4);
    return fmaxf(m5, m6);
}

DEV float expsum(f32x16& st, float m) {
    float r0 = 0.f, r1 = 0.f, r2 = 0.f, r3 = 0.f;
#pragma unroll
    for (int g = 0; g < 4; ++g) {
        float p0 = fexp2(st[4 * g + 0] - m);
        float p1 = fexp2(st[4 * g + 1] - m);
        float p2 = fexp2(st[4 * g + 2] - m);
        float p3 = fexp2(st[4 * g + 3] - m);
        st[4 * g + 0] = p0; st[4 * g + 1] = p1;
        st[4 * g + 2] = p2; st[4 * g + 3] = p3;
        r0 += p0; r1 += p1; r2 += p2; r3 += p3;
    }
    return (r0 + r1) + (r2 + r3);
}

DEV void packP(const f32x16& st, bf16x8& pb0, bf16x8& pb1, int hi) {
    u32 A0 = cvt_pk_bf16(st[0], st[1]),  A1 = cvt_pk_bf16(st[2], st[3]);
    u32 A2 = cvt_pk_bf16(st[4], st[5]),  A3 = cvt_pk_bf16(st[6], st[7]);
    u32 A4 = cvt_pk_bf16(st[8], st[9]),  A5 = cvt_pk_bf16(st[10], st[11]);
    u32 A6 = cvt_pk_bf16(st[12], st[13]), A7 = cvt_pk_bf16(st[14], st[15]);
    u32 e0 = __shfl_xor(hi ? A0 : A2, 32, 64);
    u32 e1 = __shfl_xor(hi ? A1 : A3, 32, 64);
    u32 e2 = __shfl_xor(hi ? A4 : A6, 32, 64);
    u32 e3 = __shfl_xor(hi ? A5 : A7, 32, 64);
    u32x4v w0, w1;
    w0[0] = hi ? e0 : A0;
    w0[1] = hi ? e1 : A1;
    w0[2] = hi ? A2 : e0;
    w0[3] = hi ? A3 : e1;
    w1[0] = hi ? e2 : A4;
    w1[1] = hi ? e3 : A5;
    w1[2] = hi ? A6 : e2;
    w1[3] = hi ? A7 : e3;
    pb0 = __builtin_bit_cast(bf16x8, w0);
    pb1 = __builtin_bit_cast(bf16x8, w1);
}

// ---------------------------------------------------------------------------
// Kernel 3: causal flash attention, 4-wave q-block with double-buffered
// LDS-staged K/V (R14 structure, 17.9KB LDS).  CS=16 subtiles per chunk
// (R15-validated semantics): 576 blocks, halved partial traffic.
// ---------------------------------------------------------------------------
__global__ __launch_bounds__(256) void attn_part_kernel(const u16* __restrict__ Q,
                                                        const u16* __restrict__ K,
                                                        const u16* __restrict__ Vt,
                                                        const u32* __restrict__ table,
                                                        u16* __restrict__ Opart,
                                                        float* __restrict__ Mpart,
                                                        float* __restrict__ Lpart) {
    __shared__ __align__(16) u16 Ks[2][32][68];
    __shared__ __align__(16) u16 Vs[2][64][36];

    const int tid = threadIdx.x;
    const int wave = tid >> 6, lane = tid & 63;
    const int q31 = lane & 31, hi = lane >> 5;
    const int bid = blockIdx.x;
    const int b = bid & 3;
    const u32 e = table[bid >> 2];
    const int j = (int)(e & 0xffff);
    const int c = (int)(e >> 16);
    const int qi = 4 * j + wave;              // this wave's q-tile (0..127)
    const int qr0 = qi * 32;
    const int s0 = c * 16;
    const int s1 = min(4 * j + 4, s0 + 16);   // block-uniform (CS=16)
    const int tile = (b << 7) | qi;

    const u16* Qb = Q + (size_t)b * 4096 * 64;
    const u16* Kb = K + (size_t)b * 4096 * 64;
    const u16* Vb = Vt + (size_t)b * 64 * 4096;

    // staging coords (per thread)
    const int kr = tid >> 3, ku = tid & 7;    // K: row 0..31, 16B unit 0..7
    const int vd = tid >> 2, vu = tid & 3;    // V: row 0..63, 16B unit 0..3
    const u16* ksrc = Kb + (size_t)kr * 64 + ku * 8;    // + s*2048
    const u16* vsrc = Vb + (size_t)vd * 4096 + vu * 8;  // + s*32

    bf16x8 qf[4];
#pragma unroll
    for (int kk = 0; kk < 4; ++kk)
        qf[kk] = ld_bf8(Qb + (size_t)(qr0 + q31) * 64 + kk * 16 + hi * 8);

    f32x16 o0, o1;
#pragma unroll
    for (int r = 0; r < 16; ++r) { o0[r] = 0.f; o1[r] = 0.f; }
    float m_run = -1.0e30f, l_run = 0.f;

    // prologue: stage tile s0 into buf0; prefetch tile s0+1 into regs
    ushort4 k0, k1, v0, v1;
    k0 = *reinterpret_cast<const ushort4*>(ksrc + s0 * 2048);
    k1 = *reinterpret_cast<const ushort4*>(ksrc + s0 * 2048 + 4);
    v0 = *reinterpret_cast<const ushort4*>(vsrc + s0 * 32);
    v1 = *reinterpret_cast<const ushort4*>(vsrc + s0 * 32 + 4);
    *reinterpret_cast<ushort4*>(&Ks[0][kr][ku * 8]) = k0;
    *reinterpret_cast<ushort4*>(&Ks[0][kr][ku * 8 + 4]) = k1;
    *reinterpret_cast<ushort4*>(&Vs[0][vd][vu * 8]) = v0;
    *reinterpret_cast<ushort4*>(&Vs[0][vd][vu * 8 + 4]) = v1;
    if (s0 + 1 < s1) {
        k0 = *reinterpret_cast<const ushort4*>(ksrc + (s0 + 1) * 2048);
        k1 = *reinterpret_cast<const ushort4*>(ksrc + (s0 + 1) * 2048 + 4);
        v0 = *reinterpret_cast<const ushort4*>(vsrc + (s0 + 1) * 32);
        v1 = *reinterpret_cast<const ushort4*>(vsrc + (s0 + 1) * 32 + 4);
    }
    __syncthreads();

    for (int s = s0; s < s1; ++s) {
        const int cb = (s - s0) & 1;
        if (s + 1 < s1) {
            *reinterpret_cast<ushort4*>(&Ks[cb ^ 1][kr][ku * 8]) = k0;
            *reinterpret_cast<ushort4*>(&Ks[cb ^ 1][kr][ku * 8 + 4]) = k1;
            *reinterpret_cast<ushort4*>(&Vs[cb ^ 1][vd][vu * 8]) = v0;
            *reinterpret_cast<ushort4*>(&Vs[cb ^ 1][vd][vu * 8 + 4]) = v1;
        }
        if (s + 2 < s1) {
            k0 = *reinterpret_cast<const ushort4*>(ksrc + (s + 2) * 2048);
            k1 = *reinterpret_cast<const ushort4*>(ksrc + (s + 2) * 2048 + 4);
            v0 = *reinterpret_cast<const ushort4*>(vsrc + (s + 2) * 32);
            v1 = *reinterpret_cast<const ushort4*>(vsrc + (s + 2) * 32 + 4);
        }
        if (s <= qi) {                        // wave-uniform predicate
            f32x16 st;
#pragma unroll
            for (int r = 0; r < 16; ++r) st[r] = 0.f;
#pragma unroll
            for (int kk = 0; kk < 4; ++kk) {
                bf16x8 kf = ld_lds8(&Ks[cb][q31][kk * 16 + hi * 8]);
                st = __builtin_amdgcn_mfma_f32_32x32x16_bf16(kf, qf[kk], st, 0, 0, 0);
            }
            if (s == qi) mask_diag(st, q31, hi);

            float pm = max16(st);
            pm = fmaxf(pm, __shfl_xor(pm, 32, 64));
            if (!__all(pm - m_run <= 11.5f)) {
                float mn = fmaxf(m_run, pm);
                float al = fexp2(m_run - mn);
                m_run = mn;
                l_run *= al;
#pragma unroll
                for (int r = 0; r < 16; ++r) { o0[r] *= al; o1[r] *= al; }
            }
            float rs = expsum(st, m_run);
            rs += __shfl_xor(rs, 32, 64);
            l_run += rs;

            bf16x8 p0, p1;
            packP(st, p0, p1, hi);
            bf16x8 va = ld_lds8(&Vs[cb][q31][hi * 8]);
            bf16x8 vb2 = ld_lds8(&Vs[cb][q31][16 + hi * 8]);
            bf16x8 vc = ld_lds8(&Vs[cb][32 + q31][hi * 8]);
            bf16x8 vdq = ld_lds8(&Vs[cb][32 + q31][16 + hi * 8]);
            o0 = __builtin_amdgcn_mfma_f32_32x32x16_bf16(va, p0, o0, 0, 0, 0);
            o0 = __builtin_amdgcn_mfma_f32_32x32x16_bf16(vb2, p1, o0, 0, 0, 0);
            o1 = __builtin_amdgcn_mfma_f32_32x32x16_bf16(vc, p0, o1, 0, 0, 0);
            o1 = __builtin_amdgcn_mfma_f32_32x32x16_bf16(vdq, p1, o1, 0, 0, 0);
        }
        __syncthreads();
    }

    // epilogue: wave writes its partial iff it computed anything (s0 <= qi)
    if (s0 <= qi) {
        const size_t base = (size_t)(tile * 16 + c);
        u16* Op = Opart + base * 2048;
#pragma unroll
        for (int reg = 0; reg < 16; ++reg) {
            const int crow = (reg & 3) + 8 * (reg >> 2) + 4 * hi;
            Op[crow * 32 + q31] = f2bf(o0[reg]);
            Op[(32 + crow) * 32 + q31] = f2bf(o1[reg]);
        }
        if (lane < 32) {
            Mpart[base * 32 + lane] = m_run;
            Lpart[base * 32 + lane] = l_run;
        }
    }
}

// ---------------------------------------------------------------------------
// Kernel 4: merge partials (bf16 Opart).  One block per q-tile (512 blocks).
// Double-buffered LDS + next-chunk prefetch.  nc = (qi>>4)+1 (CS=16,
// validated R15).
// ---------------------------------------------------------------------------
__global__ __launch_bounds__(256) void merge_kernel(const u16* __restrict__ Opart,
                                                    const float* __restrict__ Mpart,
                                                    const float* __restrict__ Lpart,
                                                    float* __restrict__ out) {
    __shared__ float ld[2][64 * 33];
    const int tile = blockIdx.x;            // 0..511
    const int tid = threadIdx.x;
    const int q = tid >> 3, dg = tid & 7;
    const int qi = tile & 127;
    const int nc = (qi >> 4) + 1;

    float M = -3.0e38f;
    for (int c = 0; c < nc; ++c)
        M = fmaxf(M, Mpart[(tile * 16 + c) * 32 + q]);

    float L = 0.f;
    float acc[8];
#pragma unroll
    for (int j = 0; j < 8; ++j) acc[j] = 0.f;

    const int drow = tid >> 2;
    const int qq = (tid & 3) * 8;

    u16x8v v = reinterpret_cast<const u16x8v*>(Opart + (size_t)(tile * 16) * 2048)[tid];

    for (int c = 0; c < nc; ++c) {
        const size_t base = (size_t)(tile * 16 + c);
        {
            float* dst = &ld[c & 1][drow * 33 + qq];
#pragma unroll
            for (int j = 0; j < 8; ++j) dst[j] = bf2f(v[j]);
        }
        const int cn = (c + 1 < nc) ? c + 1 : c;
        v = reinterpret_cast<const u16x8v*>(Opart + (size_t)(tile * 16 + cn) * 2048)[tid];

        __syncthreads();
        float w = fexp2(Mpart[base * 32 + q] - M);
        L += w * Lpart[base * 32 + q];
        const float* src = &ld[c & 1][0];
#pragma unroll
        for (int j = 0; j < 8; ++j)
            acc[j] += w * src[(dg * 8 + j) * 33 + q];
    }

    const float inv = 1.0f / L;
    float4 r0, r1;
    r0.x = acc[0] * inv; r0.y = acc[1] * inv; r0.z = acc[2] * inv; r0.w = acc[3] * inv;
    r1.x = acc[4] * inv; r1.y = acc[5] * inv; r1.z = acc[6] * inv; r1.w = acc[7] * inv;
    float4* dst = reinterpret_cast<float4*>(out + ((size_t)(tile * 32 + q)) * 64 + dg * 8);
    dst[0] = r0;
    dst[1] = r1;
}

// ---------------------------------------------------------------------------
extern "C" void kernel_launch(void* const* d_in, const int* in_sizes, int n_in,
                              void* d_out, int out_size, void* d_ws, size_t ws_size,
                              hipStream_t stream) {
    const float* x  = (const float*)d_in[0];
    const float* Wq = (const float*)d_in[1];
    const float* Wk = (const float*)d_in[2];
    const float* Wv = (const float*)d_in[3];
    float* out = (float*)d_out;

    char* ws = (char*)d_ws;
    const size_t MB = 1024 * 1024;
    u16* Qw  = (u16*)(ws);                     // 2 MiB
    u16* Kw  = (u16*)(ws + 2 * MB);            // 2 MiB
    u16* Vtw = (u16*)(ws + 4 * MB);            // 2 MiB
    u16* Wt  = (u16*)(ws + 6 * MB);            // 192 KiB
    u32* table = (u32*)(ws + 7 * MB);          // 576 B (144 entries)

    u16* Opart = (u16*)(ws + 8 * MB);          // 16 slots x 512 x 4KB = 32 MiB
    float* Mpart = (float*)(ws + 8 * MB + 32 * MB);
    float* Lpart = Mpart + (size_t)16 * 512 * 32;

    prep_kernel<<<386, 256, 0, stream>>>(Wq, Wk, Wv, Wt, table);
    proj_kernel<<<256, 256, 0, stream>>>(x, Wt, Qw, Kw, Vtw);
    attn_part_kernel<<<4 * 144, 256, 0, stream>>>(Qw, Kw, Vtw, table, Opart, Mpart, Lpart);
    merge_kernel<<<512, 256, 0, stream>>>(Opart, Mpart, Lpart, out);
}

// Round 17
// 67.629 us; speedup vs baseline: 1.2204x; 1.0779x over previous
//
#include <hip/hip_runtime.h>

#define DEV __device__ __forceinline__

typedef __bf16 bf16x8 __attribute__((ext_vector_type(8)));
typedef unsigned short u16x8v __attribute__((ext_vector_type(8)));
typedef float f32x4 __attribute__((ext_vector_type(4)));
typedef float f32x16 __attribute__((ext_vector_type(16)));
typedef unsigned int u32x4v __attribute__((ext_vector_type(4)));
typedef unsigned short u16;
typedef unsigned int u32;

// f32 -> bf16 bits, round-to-nearest-even (validated R1-R16, all signs)
DEV u16 f2bf(float f) {
    u32 u = __builtin_bit_cast(u32, f);
    u = (u + 0x7FFFu + ((u >> 16) & 1u)) >> 16;
    return (u16)u;
}

DEV float bf2f(u16 v) {
    return __builtin_bit_cast(float, (u32)v << 16);
}

DEV bf16x8 ld_bf8(const u16* p) {
    return *reinterpret_cast<const bf16x8*>(p);
}

// 8B-alignment-safe 16B LDS read (rows padded to 8B multiples, not 16B)
DEV bf16x8 ld_lds8(const u16* p) {
    ushort4 a = *reinterpret_cast<const ushort4*>(p);
    ushort4 b = *reinterpret_cast<const ushort4*>(p + 4);
    u16x8v o;
    o[0] = a.x; o[1] = a.y; o[2] = a.z; o[3] = a.w;
    o[4] = b.x; o[5] = b.y; o[6] = b.z; o[7] = b.w;
    return __builtin_bit_cast(bf16x8, o);
}

// raw v_exp_f32 (validated R10)
DEV float fexp2(float x) { return __builtin_amdgcn_exp2f(x); }

// pack two f32 -> one u32 of 2 bf16 (lo=a, hi=b).  Validated ONLY for a,b>=0.
DEV u32 cvt_pk_bf16(float a, float b) {
    u32 r;
    asm("v_cvt_pk_bf16_f32 %0, %1, %2" : "=v"(r) : "v"(a), "v"(b));
    return r;
}

// NOTE: v_permlane32_swap_b32 is BANNED (R5, R12 both failed absmax 0.71).
// NOTE: occupancy gate (R15 lesson): attn LDS 17.9KB (8 blk/CU), proj 2.5KB.

// ---------------------------------------------------------------------------
// Kernel 1: prep.  Blocks [0,384): weight transpose+convert (Wq pre-scaled by
// 1/sqrt(512)*log2(e)).  Blocks [384,386): build 144-entry chunk table:
// q-block j (tiles 4j..4j+3) has (j>>2)+1 chunks of 16 subtiles (CS=16,
// validated R15/R16).
// ---------------------------------------------------------------------------
__global__ __launch_bounds__(256) void prep_kernel(const float* __restrict__ W0,
                                                   const float* __restrict__ W1,
                                                   const float* __restrict__ W2,
                                                   u16* __restrict__ Wt,
                                                   u32* __restrict__ table) {
    const int blk = blockIdx.x;
    if (blk < 384) {
        int idx = blk * 256 + threadIdx.x;   // 3*64*512 = 98304
        int w = idx >> 15, rem = idx & 32767, h = rem >> 9, c = rem & 511;
        const float* W = (w == 0) ? W0 : ((w == 1) ? W1 : W2);
        float v = W[c * 64 + h];
        if (w == 0) v *= 0.044194173824159216f * 1.4426950408889634f;  // SCL*log2e
        Wt[idx] = f2bf(v);
    } else {
        int idx = (blk - 384) * 256 + threadIdx.x;   // < 512
        if (idx < 512) {
            int j = idx >> 4, k = idx & 15;          // j = 0..31
            int nch = (j >> 2) + 1;
            if (k < nch) {
                int base = 0;
                for (int i = 0; i < j; ++i) base += (i >> 2) + 1;
                table[base + k] = (u32)j | ((u32)k << 16);
            }
        }
    }
}

// ---------------------------------------------------------------------------
// Kernel 2: QKV projection, BARRIER-FREE 1-wave blocks (64 thr), 16 rows each.
// Wave-private double-buffered LDS staging (2.5KB): stage kk slab (16x32,
// f32->bf16) while computing previous slab.  Per-wave math identical to the
// R11/R14/R16-validated kernel (same pitch-40 LDS, same fragment reads).
// 1024 blocks; zero __syncthreads (wave-local RAW ordered by compiler).
// ---------------------------------------------------------------------------
__global__ __launch_bounds__(64) void proj_kernel(const float* __restrict__ x,
                                                  const u16* __restrict__ Wt,
                                                  u16* __restrict__ Q,
                                                  u16* __restrict__ Kq,
                                                  u16* __restrict__ Vt) {
    __shared__ __align__(16) u16 xs[2][16][40];
    const int lane = threadIdx.x;
    const int lr = lane & 15, lg = lane >> 4;
    const int r0 = blockIdx.x * 16;
    // staging: 128 float4-units per slab; thread t owns units 2t, 2t+1:
    // row = u>>3 (0..15), cu = u&7 (col4)
    const int u0 = 2 * lane, u1 = 2 * lane + 1;
    const int sr0 = u0 >> 3, sc0 = (u0 & 7) * 4;
    const int sr1 = u1 >> 3, sc1 = (u1 & 7) * 4;

    f32x4 acc[3][4];
#pragma unroll
    for (int m = 0; m < 3; ++m)
#pragma unroll
        for (int b = 0; b < 4; ++b) acc[m][b] = (f32x4){0.f, 0.f, 0.f, 0.f};

    float4 a0, a1;
#define PLOAD(KK)                                                               \
    {   a0 = *reinterpret_cast<const float4*>(x + (size_t)(r0 + sr0) * 512 + (KK) * 32 + sc0); \
        a1 = *reinterpret_cast<const float4*>(x + (size_t)(r0 + sr1) * 512 + (KK) * 32 + sc1); }
#define PSTORE(BUF)                                                             \
    {   ushort4 h0, h1;                                                         \
        h0.x = f2bf(a0.x); h0.y = f2bf(a0.y); h0.z = f2bf(a0.z); h0.w = f2bf(a0.w); \
        h1.x = f2bf(a1.x); h1.y = f2bf(a1.y); h1.z = f2bf(a1.z); h1.w = f2bf(a1.w); \
        *reinterpret_cast<ushort4*>(&xs[BUF][sr0][sc0]) = h0;                   \
        *reinterpret_cast<ushort4*>(&xs[BUF][sr1][sc1]) = h1;  }

    PLOAD(0);
    PSTORE(0);
    PLOAD(1);

    for (int kk = 0; kk < 16; ++kk) {
        const int buf = kk & 1;
        if (kk + 1 < 16) PSTORE(buf ^ 1);
        if (kk + 2 < 16) PLOAD(kk + 2);

        bf16x8 af = ld_bf8(&xs[buf][lr][lg * 8]);
#pragma unroll
        for (int m = 0; m < 3; ++m) {
#pragma unroll
            for (int nt = 0; nt < 4; ++nt) {
                bf16x8 bf = ld_bf8(Wt + m * 32768 + (lr + 16 * nt) * 512 + kk * 32 + lg * 8);
                acc[m][nt] = __builtin_amdgcn_mfma_f32_16x16x32_bf16(af, bf, acc[m][nt], 0, 0, 0);
            }
        }
    }
#undef PLOAD
#undef PSTORE

    const int rw = r0;
#pragma unroll
    for (int nt = 0; nt < 4; ++nt) {
        const int h = lr + 16 * nt;
#pragma unroll
        for (int reg = 0; reg < 4; ++reg) {
            Q[(size_t)(rw + 4 * lg + reg) * 64 + h]  = f2bf(acc[0][nt][reg]);
            Kq[(size_t)(rw + 4 * lg + reg) * 64 + h] = f2bf(acc[1][nt][reg]);
        }
    }
    const int bidx = rw >> 12;
    const int t0 = (rw & 4095) + 4 * lg;
#pragma unroll
    for (int nt = 0; nt < 4; ++nt) {
        const int h = lr + 16 * nt;
        ushort4 hv;
        hv.x = f2bf(acc[2][nt][0]); hv.y = f2bf(acc[2][nt][1]);
        hv.z = f2bf(acc[2][nt][2]); hv.w = f2bf(acc[2][nt][3]);
        *reinterpret_cast<ushort4*>(Vt + ((size_t)(bidx * 64 + h)) * 4096 + t0) = hv;
    }
}

// ---------------------------------------------------------------------------
// Attention math helpers (byte-identical to R13/R14/R16-validated versions)
// ---------------------------------------------------------------------------
DEV void mask_diag(f32x16& st, int q31, int hi) {
#pragma unroll
    for (int reg = 0; reg < 16; ++reg) {
        const int crow = (reg & 3) + 8 * (reg >> 2) + 4 * hi;
        if (crow > q31) st[reg] = -3.0e38f;
    }
}

DEV float max16(const f32x16& a) {
    float m0 = fmaxf(fmaxf(a[0], a[1]), a[2]);
    float m1 = fmaxf(fmaxf(a[3], a[4]), a[5]);
    float m2 = fmaxf(fmaxf(a[6], a[7]), a[8]);
    float m3 = fmaxf(fmaxf(a[9], a[10]), a[11]);
    float m4 = fmaxf(fmaxf(a[12], a[13]), a[14]);
    float m5 = fmaxf(fmaxf(m0, m1), a[15]);
    float m6 = fmaxf(fmaxf(m2, m3), m4);
    return fmaxf(m5, m6);
}

DEV float expsum(f32x16& st, float m) {
    float r0 = 0.f, r1 = 0.f, r2 = 0.f, r3 = 0.f;
#pragma unroll
    for (int g = 0; g < 4; ++g) {
        float p0 = fexp2(st[4 * g + 0] - m);
        float p1 = fexp2(st[4 * g + 1] - m);
        float p2 = fexp2(st[4 * g + 2] - m);
        float p3 = fexp2(st[4 * g + 3] - m);
        st[4 * g + 0] = p0; st[4 * g + 1] = p1;
        st[4 * g + 2] = p2; st[4 * g + 3] = p3;
        r0 += p0; r1 += p1; r2 += p2; r3 += p3;
    }
    return (r0 + r1) + (r2 + r3);
}

DEV void packP(const f32x16& st, bf16x8& pb0, bf16x8& pb1, int hi) {
    u32 A0 = cvt_pk_bf16(st[0], st[1]),  A1 = cvt_pk_bf16(st[2], st[3]);
    u32 A2 = cvt_pk_bf16(st[4], st[5]),  A3 = cvt_pk_bf16(st[6], st[7]);
    u32 A4 = cvt_pk_bf16(st[8], st[9]),  A5 = cvt_pk_bf16(st[10], st[11]);
    u32 A6 = cvt_pk_bf16(st[12], st[13]), A7 = cvt_pk_bf16(st[14], st[15]);
    u32 e0 = __shfl_xor(hi ? A0 : A2, 32, 64);
    u32 e1 = __shfl_xor(hi ? A1 : A3, 32, 64);
    u32 e2 = __shfl_xor(hi ? A4 : A6, 32, 64);
    u32 e3 = __shfl_xor(hi ? A5 : A7, 32, 64);
    u32x4v w0, w1;
    w0[0] = hi ? e0 : A0;
    w0[1] = hi ? e1 : A1;
    w0[2] = hi ? A2 : e0;
    w0[3] = hi ? A3 : e1;
    w1[0] = hi ? e2 : A4;
    w1[1] = hi ? e3 : A5;
    w1[2] = hi ? A6 : e2;
    w1[3] = hi ? A7 : e3;
    pb0 = __builtin_bit_cast(bf16x8, w0);
    pb1 = __builtin_bit_cast(bf16x8, w1);
}

// ---------------------------------------------------------------------------
// Kernel 3: causal flash attention, 4-wave q-block with double-buffered
// LDS-staged K/V (R14 structure, 17.9KB LDS).  CS=16 chunks (R15/R16).
// Table read REVERSED so longest chains (large j) dispatch first (tail fix).
// ---------------------------------------------------------------------------
__global__ __launch_bounds__(256) void attn_part_kernel(const u16* __restrict__ Q,
                                                        const u16* __restrict__ K,
                                                        const u16* __restrict__ Vt,
                                                        const u32* __restrict__ table,
                                                        u16* __restrict__ Opart,
                                                        float* __restrict__ Mpart,
                                                        float* __restrict__ Lpart) {
    __shared__ __align__(16) u16 Ks[2][32][68];
    __shared__ __align__(16) u16 Vs[2][64][36];

    const int tid = threadIdx.x;
    const int wave = tid >> 6, lane = tid & 63;
    const int q31 = lane & 31, hi = lane >> 5;
    const int bid = blockIdx.x;
    const int b = bid & 3;
    const u32 e = table[143 - (bid >> 2)];    // reversed: longest chains first
    const int j = (int)(e & 0xffff);
    const int c = (int)(e >> 16);
    const int qi = 4 * j + wave;              // this wave's q-tile (0..127)
    const int qr0 = qi * 32;
    const int s0 = c * 16;
    const int s1 = min(4 * j + 4, s0 + 16);   // block-uniform (CS=16)
    const int tile = (b << 7) | qi;

    const u16* Qb = Q + (size_t)b * 4096 * 64;
    const u16* Kb = K + (size_t)b * 4096 * 64;
    const u16* Vb = Vt + (size_t)b * 64 * 4096;

    // staging coords (per thread)
    const int kr = tid >> 3, ku = tid & 7;    // K: row 0..31, 16B unit 0..7
    const int vd = tid >> 2, vu = tid & 3;    // V: row 0..63, 16B unit 0..3
    const u16* ksrc = Kb + (size_t)kr * 64 + ku * 8;    // + s*2048
    const u16* vsrc = Vb + (size_t)vd * 4096 + vu * 8;  // + s*32

    bf16x8 qf[4];
#pragma unroll
    for (int kk = 0; kk < 4; ++kk)
        qf[kk] = ld_bf8(Qb + (size_t)(qr0 + q31) * 64 + kk * 16 + hi * 8);

    f32x16 o0, o1;
#pragma unroll
    for (int r = 0; r < 16; ++r) { o0[r] = 0.f; o1[r] = 0.f; }
    float m_run = -1.0e30f, l_run = 0.f;

    // prologue: stage tile s0 into buf0; prefetch tile s0+1 into regs
    ushort4 k0, k1, v0, v1;
    k0 = *reinterpret_cast<const ushort4*>(ksrc + s0 * 2048);
    k1 = *reinterpret_cast<const ushort4*>(ksrc + s0 * 2048 + 4);
    v0 = *reinterpret_cast<const ushort4*>(vsrc + s0 * 32);
    v1 = *reinterpret_cast<const ushort4*>(vsrc + s0 * 32 + 4);
    *reinterpret_cast<ushort4*>(&Ks[0][kr][ku * 8]) = k0;
    *reinterpret_cast<ushort4*>(&Ks[0][kr][ku * 8 + 4]) = k1;
    *reinterpret_cast<ushort4*>(&Vs[0][vd][vu * 8]) = v0;
    *reinterpret_cast<ushort4*>(&Vs[0][vd][vu * 8 + 4]) = v1;
    if (s0 + 1 < s1) {
        k0 = *reinterpret_cast<const ushort4*>(ksrc + (s0 + 1) * 2048);
        k1 = *reinterpret_cast<const ushort4*>(ksrc + (s0 + 1) * 2048 + 4);
        v0 = *reinterpret_cast<const ushort4*>(vsrc + (s0 + 1) * 32);
        v1 = *reinterpret_cast<const ushort4*>(vsrc + (s0 + 1) * 32 + 4);
    }
    __syncthreads();

    for (int s = s0; s < s1; ++s) {
        const int cb = (s - s0) & 1;
        if (s + 1 < s1) {
            *reinterpret_cast<ushort4*>(&Ks[cb ^ 1][kr][ku * 8]) = k0;
            *reinterpret_cast<ushort4*>(&Ks[cb ^ 1][kr][ku * 8 + 4]) = k1;
            *reinterpret_cast<ushort4*>(&Vs[cb ^ 1][vd][vu * 8]) = v0;
            *reinterpret_cast<ushort4*>(&Vs[cb ^ 1][vd][vu * 8 + 4]) = v1;
        }
        if (s + 2 < s1) {
            k0 = *reinterpret_cast<const ushort4*>(ksrc + (s + 2) * 2048);
            k1 = *reinterpret_cast<const ushort4*>(ksrc + (s + 2) * 2048 + 4);
            v0 = *reinterpret_cast<const ushort4*>(vsrc + (s + 2) * 32);
            v1 = *reinterpret_cast<const ushort4*>(vsrc + (s + 2) * 32 + 4);
        }
        if (s <= qi) {                        // wave-uniform predicate
            f32x16 st;
#pragma unroll
            for (int r = 0; r < 16; ++r) st[r] = 0.f;
#pragma unroll
            for (int kk = 0; kk < 4; ++kk) {
                bf16x8 kf = ld_lds8(&Ks[cb][q31][kk * 16 + hi * 8]);
                st = __builtin_amdgcn_mfma_f32_32x32x16_bf16(kf, qf[kk], st, 0, 0, 0);
            }
            if (s == qi) mask_diag(st, q31, hi);

            float pm = max16(st);
            pm = fmaxf(pm, __shfl_xor(pm, 32, 64));
            if (!__all(pm - m_run <= 11.5f)) {
                float mn = fmaxf(m_run, pm);
                float al = fexp2(m_run - mn);
                m_run = mn;
                l_run *= al;
#pragma unroll
                for (int r = 0; r < 16; ++r) { o0[r] *= al; o1[r] *= al; }
            }
            float rs = expsum(st, m_run);
            rs += __shfl_xor(rs, 32, 64);
            l_run += rs;

            bf16x8 p0, p1;
            packP(st, p0, p1, hi);
            bf16x8 va = ld_lds8(&Vs[cb][q31][hi * 8]);
            bf16x8 vb2 = ld_lds8(&Vs[cb][q31][16 + hi * 8]);
            bf16x8 vc = ld_lds8(&Vs[cb][32 + q31][hi * 8]);
            bf16x8 vdq = ld_lds8(&Vs[cb][32 + q31][16 + hi * 8]);
            o0 = __builtin_amdgcn_mfma_f32_32x32x16_bf16(va, p0, o0, 0, 0, 0);
            o0 = __builtin_amdgcn_mfma_f32_32x32x16_bf16(vb2, p1, o0, 0, 0, 0);
            o1 = __builtin_amdgcn_mfma_f32_32x32x16_bf16(vc, p0, o1, 0, 0, 0);
            o1 = __builtin_amdgcn_mfma_f32_32x32x16_bf16(vdq, p1, o1, 0, 0, 0);
        }
        __syncthreads();
    }

    // epilogue: wave writes its partial iff it computed anything (s0 <= qi)
    if (s0 <= qi) {
        const size_t base = (size_t)(tile * 16 + c);
        u16* Op = Opart + base * 2048;
#pragma unroll
        for (int reg = 0; reg < 16; ++reg) {
            const int crow = (reg & 3) + 8 * (reg >> 2) + 4 * hi;
            Op[crow * 32 + q31] = f2bf(o0[reg]);
            Op[(32 + crow) * 32 + q31] = f2bf(o1[reg]);
        }
        if (lane < 32) {
            Mpart[base * 32 + lane] = m_run;
            Lpart[base * 32 + lane] = l_run;
        }
    }
}

// ---------------------------------------------------------------------------
// Kernel 4: merge partials (bf16 Opart).  One block per q-tile (512 blocks).
// Double-buffered LDS + next-chunk prefetch.  nc = (qi>>4)+1 (CS=16,
// validated R15/R16).
// ---------------------------------------------------------------------------
__global__ __launch_bounds__(256) void merge_kernel(const u16* __restrict__ Opart,
                                                    const float* __restrict__ Mpart,
                                                    const float* __restrict__ Lpart,
                                                    float* __restrict__ out) {
    __shared__ float ld[2][64 * 33];
    const int tile = blockIdx.x;            // 0..511
    const int tid = threadIdx.x;
    const int q = tid >> 3, dg = tid & 7;
    const int qi = tile & 127;
    const int nc = (qi >> 4) + 1;

    float M = -3.0e38f;
    for (int c = 0; c < nc; ++c)
        M = fmaxf(M, Mpart[(tile * 16 + c) * 32 + q]);

    float L = 0.f;
    float acc[8];
#pragma unroll
    for (int j = 0; j < 8; ++j) acc[j] = 0.f;

    const int drow = tid >> 2;
    const int qq = (tid & 3) * 8;

    u16x8v v = reinterpret_cast<const u16x8v*>(Opart + (size_t)(tile * 16) * 2048)[tid];

    for (int c = 0; c < nc; ++c) {
        const size_t base = (size_t)(tile * 16 + c);
        {
            float* dst = &ld[c & 1][drow * 33 + qq];
#pragma unroll
            for (int j = 0; j < 8; ++j) dst[j] = bf2f(v[j]);
        }
        const int cn = (c + 1 < nc) ? c + 1 : c;
        v = reinterpret_cast<const u16x8v*>(Opart + (size_t)(tile * 16 + cn) * 2048)[tid];

        __syncthreads();
        float w = fexp2(Mpart[base * 32 + q] - M);
        L += w * Lpart[base * 32 + q];
        const float* src = &ld[c & 1][0];
#pragma unroll
        for (int j = 0; j < 8; ++j)
            acc[j] += w * src[(dg * 8 + j) * 33 + q];
    }

    const float inv = 1.0f / L;
    float4 r0, r1;
    r0.x = acc[0] * inv; r0.y = acc[1] * inv; r0.z = acc[2] * inv; r0.w = acc[3] * inv;
    r1.x = acc[4] * inv; r1.y = acc[5] * inv; r1.z = acc[6] * inv; r1.w = acc[7] * inv;
    float4* dst = reinterpret_cast<float4*>(out + ((size_t)(tile * 32 + q)) * 64 + dg * 8);
    dst[0] = r0;
    dst[1] = r1;
}

// ---------------------------------------------------------------------------
extern "C" void kernel_launch(void* const* d_in, const int* in_sizes, int n_in,
                              void* d_out, int out_size, void* d_ws, size_t ws_size,
                              hipStream_t stream) {
    const float* x  = (const float*)d_in[0];
    const float* Wq = (const float*)d_in[1];
    const float* Wk = (const float*)d_in[2];
    const float* Wv = (const float*)d_in[3];
    float* out = (float*)d_out;

    char* ws = (char*)d_ws;
    const size_t MB = 1024 * 1024;
    u16* Qw  = (u16*)(ws);                     // 2 MiB
    u16* Kw  = (u16*)(ws + 2 * MB);            // 2 MiB
    u16* Vtw = (u16*)(ws + 4 * MB);            // 2 MiB
    u16* Wt  = (u16*)(ws + 6 * MB);            // 192 KiB
    u32* table = (u32*)(ws + 7 * MB);          // 576 B (144 entries)

    u16* Opart = (u16*)(ws + 8 * MB);          // 16 slots x 512 x 4KB = 32 MiB
    float* Mpart = (float*)(ws + 8 * MB + 32 * MB);
    float* Lpart = Mpart + (size_t)16 * 512 * 32;

    prep_kernel<<<386, 256, 0, stream>>>(Wq, Wk, Wv, Wt, table);
    proj_kernel<<<1024, 64, 0, stream>>>(x, Wt, Qw, Kw, Vtw);
    attn_part_kernel<<<4 * 144, 256, 0, stream>>>(Qw, Kw, Vtw, table, Opart, Mpart, Lpart);
    merge_kernel<<<512, 256, 0, stream>>>(Opart, Mpart, Lpart, out);
}